// Round 9
// baseline (278.797 us; speedup 1.0000x reference)
//
#include <hip/hip_runtime.h>
#include <cstdint>
#include <cstddef>

#define NPIX (512 * 512)
#define NMAPS 64
#define NPTS 300
#define CAP 2048          // global candidate cap per map (mean ~700)
#define LCAP 640          // per-block LDS candidate cap (mean ~44)
#define NWORDS 4096       // 262144 bits / 64
#define TARGET 700.0      // expected survivor count per map

__device__ __forceinline__ uint32_t umin32(uint32_t a, uint32_t b) {
  return a < b ? a : b;
}

// ---------------------------------------------------------------------------
// Threefry-2x32, 20 rounds (exactly JAX's formulation).
// ---------------------------------------------------------------------------
__device__ __forceinline__ void tf2x32(uint32_t k0, uint32_t k1,
                                       uint32_t x0, uint32_t x1,
                                       uint32_t& o0, uint32_t& o1) {
  uint32_t ks2 = k0 ^ k1 ^ 0x1BD11BDAu;
#define TFR(r) { x0 += x1; x1 = (x1 << (r)) | (x1 >> (32 - (r))); x1 ^= x0; }
  x0 += k0; x1 += k1;
  TFR(13) TFR(15) TFR(26) TFR(6)
  x0 += k1; x1 += ks2 + 1u;
  TFR(17) TFR(29) TFR(16) TFR(24)
  x0 += ks2; x1 += k0 + 2u;
  TFR(13) TFR(15) TFR(26) TFR(6)
  x0 += k0; x1 += k1 + 3u;
  TFR(17) TFR(29) TFR(16) TFR(24)
  x0 += k1; x1 += ks2 + 4u;
  TFR(13) TFR(15) TFR(26) TFR(6)
  x0 += ks2; x1 += k0 + 5u;
#undef TFR
  o0 = x0; o1 = x1;
}

// partitionable threefry: bits at flat pixel p = o0^o1 of block (0,p);
// uniform f32 keeps mantissa bits>>9 (monotone) — compare as 23-bit ints.
__device__ __forceinline__ uint32_t score23(uint32_t k0, uint32_t k1, uint32_t p) {
  uint32_t a, b;
  tf2x32(k0, k1, 0u, p, a, b);
  return (a ^ b) >> 9;
}

__device__ __forceinline__ void map_key(int m, uint32_t& k0, uint32_t& k1) {
  tf2x32(0u, 42u, 0u, (uint32_t)m, k0, k1);  // split(key(42),64)[m]
}

__device__ __forceinline__ uint32_t thr_from_N(unsigned int N) {
  return ((double)N > TARGET)
             ? (uint32_t)(8388608.0 * (1.0 - TARGET / (double)N))
             : 0u;
}

// DPP helper for the min-reduce (structure HW-validated rounds 4/5).
// CTRL must be a compile-time constant (ICE) -> template parameter.
template <int CTRL>
__device__ __forceinline__ float dpp_mov_f32(float x) {
  return __uint_as_float((uint32_t)__builtin_amdgcn_update_dpp(
      (int)__float_as_uint(x), (int)__float_as_uint(x), CTRL, 0xF, 0xF,
      false));
}

// wave-64 float min reduction: 4x row_shr + row_bcast15 + row_bcast31,
// result at lane 63, broadcast via readlane.
__device__ __forceinline__ float wave_min_f32_bcast(float v) {
  v = fminf(v, dpp_mov_f32<0x111>(v));  // row_shr:1
  v = fminf(v, dpp_mov_f32<0x112>(v));  // row_shr:2
  v = fminf(v, dpp_mov_f32<0x114>(v));  // row_shr:4
  v = fminf(v, dpp_mov_f32<0x118>(v));  // row_shr:8
  v = fminf(v, dpp_mov_f32<0x142>(v));  // row_bcast:15
  v = fminf(v, dpp_mov_f32<0x143>(v));  // row_bcast:31
  return __uint_as_float(
      (uint32_t)__builtin_amdgcn_readlane((int)__float_as_uint(v), 63));
}

// ---------------------------------------------------------------------------
// K1: wave-rolling Sobel. One wave owns a 64x32 strip; rows roll through
// registers; column neighbors via __shfl (round-5-validated). Ballot IS the
// bitmap word. Per-wave counts to disjoint slots (zero atomics). Zeroes gcnt.
// ---------------------------------------------------------------------------
__global__ __launch_bounds__(256) void edge_mask_kernel(
    const float* __restrict__ mo, const float* __restrict__ lb,
    unsigned long long* __restrict__ bitmap, unsigned int* __restrict__ wcnts,
    unsigned int* __restrict__ gcnt) {
  const int m = blockIdx.y;
  const int which = m & 1;
  const float* __restrict__ src = (which ? lb : mo) + (size_t)(m >> 1) * NPIX;
  const int l = threadIdx.x & 63;
  const int wi = blockIdx.x * 4 + (threadIdx.x >> 6);  // [0,128)
  const int cs = wi & 7;        // column strip
  const int seg = wi >> 3;      // row segment
  const int y0 = seg * 32;
  const int X = cs * 64 + l;
  const int hcol = (l == 0) ? X - 1 : ((l == 63) ? X + 1 : -1);

  if (blockIdx.x == 0 && m == 0 && threadIdx.x < 64) gcnt[threadIdx.x] = 0;

  auto sig = [&](float t) { return which ? t : 1.f / (1.f + expf(-t)); };
  auto ldmain = [&](int row) -> float {
    return ((unsigned)row < 512u) ? sig(src[row * 512 + X]) : 0.f;
  };
  auto ldhalo = [&](int row) -> float {
    return ((unsigned)row < 512u && (unsigned)hcol < 512u)
               ? sig(src[row * 512 + hcol]) : 0.f;
  };

  float a = ldmain(y0 - 1), ha = ldhalo(y0 - 1);
  float b = ldmain(y0),     hb = ldhalo(y0);
  unsigned int cnt = 0;

  for (int i = 0; i < 32; ++i) {
    const int y = y0 + i;
    float c = ldmain(y + 1), hc = ldhalo(y + 1);

    // ha holds LEFT halo in lane 0 and RIGHT halo in lane 63.
    float aL = __shfl_up(a, 1);   if (l == 0)  aL = ha;
    float aR = __shfl_down(a, 1); if (l == 63) aR = ha;
    float bL = __shfl_up(b, 1);   if (l == 0)  bL = hb;
    float bR = __shfl_down(b, 1); if (l == 63) bR = hb;
    float cL = __shfl_up(c, 1);   if (l == 0)  cL = hc;
    float cR = __shfl_down(c, 1); if (l == 63) cR = hc;

    float ex = (aR - aL) + 2.f * (bR - bL) + (cR - cL);
    float ey = (cL + 2.f * c + cR) - (aL + 2.f * a + aR);
    float edge = sqrtf(ex * ex + ey * ey);
    bool bit = edge > 0.5f;

    unsigned long long ball = __ballot(bit);
    if (l == 0) {
      bitmap[(size_t)m * NWORDS + (size_t)y * 8 + cs] = ball;
      cnt += (unsigned int)__popcll(ball);
    }
    a = b; ha = hb; b = c; hb = hc;
  }
  if (l == 0) wcnts[m * 128 + wi] = cnt;
}

// block-level N = sum of the 128 per-wave counts (wave 0 does it; result in
// LDS). Callers must __syncthreads() after.
__device__ __forceinline__ void reduce_N(const unsigned int* __restrict__ wcnts,
                                         int m, int tid, unsigned int* sN) {
  if (tid < 64) {
    unsigned int v = wcnts[m * 128 + tid] + wcnts[m * 128 + 64 + tid];
#pragma unroll
    for (int off = 32; off > 0; off >>= 1) v += __shfl_xor(v, off, 64);
    if (tid == 0) *sN = v;
  }
}

// ---------------------------------------------------------------------------
// K2a: grid-wide candidate collection (N computed in-block from wcnts).
// ---------------------------------------------------------------------------
__global__ __launch_bounds__(256) void collect_kernel(
    const unsigned long long* __restrict__ bitmap,
    const unsigned int* __restrict__ wcnts,
    unsigned long long* __restrict__ cand, unsigned int* __restrict__ gcnt) {
  const int m = blockIdx.y;
  const int tid = threadIdx.x;
  const int w = blockIdx.x * 256 + tid;

  __shared__ unsigned long long lbuf[LCAP];
  __shared__ unsigned int lcnt;
  __shared__ unsigned int lbase;
  __shared__ unsigned int sN;
  if (tid == 0) lcnt = 0;
  reduce_N(wcnts, m, tid, &sN);
  __syncthreads();

  const unsigned int N = sN;
  if (N) {
    const uint32_t mt = thr_from_N(N);
    uint32_t k0, k1;
    map_key(m, k0, k1);
    unsigned long long word = bitmap[(size_t)m * NWORDS + w];
    while (word) {
      int bpos = __builtin_ctzll(word);
      word &= word - 1;
      uint32_t p = ((uint32_t)w << 6) + (uint32_t)bpos;
      uint32_t sc = score23(k0, k1, p);
      if (sc >= mt) {
        unsigned int pos = atomicAdd(&lcnt, 1u);
        if (pos < LCAP)
          lbuf[pos] = ((unsigned long long)sc << 32) | (uint32_t)(~p);
      }
    }
  }
  __syncthreads();
  unsigned int c = lcnt < LCAP ? lcnt : LCAP;
  if (tid == 0)
    lbase = atomicAdd(&gcnt[m], lcnt + (lcnt > LCAP ? 0x1000000u : 0u));
  __syncthreads();
  for (unsigned int i = tid; i < c; i += 256) {
    unsigned int pos = lbase + i;
    if (pos < CAP) cand[(size_t)m * CAP + pos] = lbuf[i];
  }
}

// ---------------------------------------------------------------------------
// K2b: radix-SELECT (only the top-`need` SET matters; MST is order/start
// invariant). Fallback exact rescan if collection overflowed/short.
// ---------------------------------------------------------------------------
__global__ __launch_bounds__(256) void select_kernel(
    const unsigned long long* __restrict__ bitmap,
    const unsigned int* __restrict__ wcnts,
    const unsigned long long* __restrict__ cand,
    const unsigned int* __restrict__ gcnt,
    uint32_t* __restrict__ pts, unsigned int* __restrict__ nsel) {
  const int m = blockIdx.x;
  const int tid = threadIdx.x;
  __shared__ unsigned long long buf[CAP];
  __shared__ unsigned int hist[256];
  __shared__ unsigned int s_tot, s_cnt, s_b, s_rank, sN;

  reduce_N(wcnts, m, tid, &sN);
  __syncthreads();
  const unsigned int N = sN;
  if (N == 0) { if (tid == 0) nsel[m] = 0; return; }
  const unsigned int need = N < NPTS ? N : NPTS;

  unsigned int c;
  const unsigned int g = gcnt[m];
  if (g >= need && g <= CAP) {
    c = g;
    for (unsigned int i = tid; i < c; i += 256)
      buf[i] = cand[(size_t)m * CAP + i];
    __syncthreads();
  } else {
    // fallback: exact iterative rescan of the bitmap
    uint32_t k0, k1;
    map_key(m, k0, k1);
    const unsigned long long* __restrict__ wmap = bitmap + (size_t)m * NWORDS;
    unsigned int mt = 0, cnt = 0;
    double target = TARGET;
    for (int iter = 0; iter < 16; ++iter) {
      mt = ((double)N > target)
               ? (unsigned int)(8388608.0 * (1.0 - target / (double)N))
               : 0u;
      if (tid == 0) s_tot = 0;
      __syncthreads();
      unsigned int lc = 0;
      for (int w = tid; w < NWORDS; w += 256) {
        unsigned long long word = wmap[w];
        while (word) {
          int bpos = __builtin_ctzll(word);
          word &= word - 1;
          uint32_t p = ((uint32_t)w << 6) + (uint32_t)bpos;
          lc += (score23(k0, k1, p) >= mt) ? 1u : 0u;
        }
      }
      if (lc) atomicAdd(&s_tot, lc);
      __syncthreads();
      cnt = s_tot;
      __syncthreads();
      if (cnt >= need && cnt <= CAP) break;
      if (cnt < need) target *= 3.0; else target *= 0.5;
    }
    if (tid == 0) s_cnt = 0;
    __syncthreads();
    for (int w = tid; w < NWORDS; w += 256) {
      unsigned long long word = wmap[w];
      while (word) {
        int bpos = __builtin_ctzll(word);
        word &= word - 1;
        uint32_t p = ((uint32_t)w << 6) + (uint32_t)bpos;
        uint32_t sc = score23(k0, k1, p);
        if (sc >= mt) {
          unsigned int pos = atomicAdd(&s_cnt, 1u);
          if (pos < CAP)
            buf[pos] = ((unsigned long long)sc << 32) | (uint32_t)(~p);
        }
      }
    }
    __syncthreads();
    c = s_cnt < CAP ? s_cnt : CAP;
    __syncthreads();
  }

  unsigned long long T = 0ull;
  if (c > need) {
    unsigned int rank = need;
    unsigned long long prefix = 0ull;
    for (int sh = 48; sh >= 0; sh -= 8) {
      hist[tid] = 0;
      __syncthreads();
      for (unsigned int i = tid; i < c; i += 256) {
        unsigned long long k = buf[i];
        if ((k >> (sh + 8)) == (prefix >> (sh + 8)))
          atomicAdd(&hist[(unsigned int)(k >> sh) & 255u], 1u);
      }
      __syncthreads();
      if (tid < 64) {
        unsigned int h0 = hist[4 * tid], h1 = hist[4 * tid + 1];
        unsigned int h2 = hist[4 * tid + 2], h3 = hist[4 * tid + 3];
        unsigned int gsum = h0 + h1 + h2 + h3;
        unsigned int s = gsum;
#pragma unroll
        for (int off = 1; off < 64; off <<= 1) {
          unsigned int o = __shfl_down(s, off, 64);
          s += (tid + off < 64) ? o : 0u;
        }
        unsigned int above = s - gsum;  // strictly higher digits
        unsigned int S3 = above, S2 = S3 + h3, S1 = S2 + h2, S0 = S1 + h1;
        if (S3 < rank && rank <= S3 + h3) { s_b = 4 * tid + 3; s_rank = rank - S3; }
        if (S2 < rank && rank <= S2 + h2) { s_b = 4 * tid + 2; s_rank = rank - S2; }
        if (S1 < rank && rank <= S1 + h1) { s_b = 4 * tid + 1; s_rank = rank - S1; }
        if (S0 < rank && rank <= S0 + h0) { s_b = 4 * tid + 0; s_rank = rank - S0; }
      }
      __syncthreads();
      prefix |= ((unsigned long long)s_b) << sh;
      rank = s_rank;
    }
    T = prefix;  // exact need-th largest key
  }

  if (tid == 0) s_cnt = 0;
  __syncthreads();
  for (unsigned int i = tid; i < c; i += 256) {
    unsigned long long k = buf[i];
    if (k >= T) {
      unsigned int pos = atomicAdd(&s_cnt, 1u);
      if (pos < NPTS) {
        uint32_t p = ~(uint32_t)k;
        pts[(size_t)m * NPTS + pos] = ((p >> 9) << 16) | (p & 511u);
      }
    }
  }
  __syncthreads();
  if (tid == 0) nsel[m] = s_cnt < need ? s_cnt : need;
}

// ---------------------------------------------------------------------------
// K3: Prim MST, one wave/map, ALL-FLOAT (coords<512 => d2<2^20, exact in f32).
// ROUND-8 BUG FIX: dead slots (in-tree or id>=n) must stay pinned at INF.
// The float rewrite had md[k]=fminf(md[k],nd) unguarded, so removed vertices
// and (0,0)-phantom invalid slots re-entered the frontier. Now a per-lane
// 5-bit tmask marks dead slots and the update is md=dead?INF:fminf(md,nd) —
// exactly the int version's sentinel semantics (which passed absmax 0).
// ---------------------------------------------------------------------------
__global__ __launch_bounds__(64, 1) void mst_kernel(
    const uint32_t* __restrict__ pts, const unsigned int* __restrict__ nsel,
    float* __restrict__ tps) {
  const int m = blockIdx.x;
  const int l = threadIdx.x;
  const int n = (int)nsel[m];
  if (n <= 1) { if (l == 0) tps[m] = 0.f; return; }
  const float INF = __int_as_float(0x7f800000);

  float fx[5], fy[5], md[5];
  int tmask = 0;  // bit k set => slot k*64+l is dead (in-tree or invalid)
#pragma unroll
  for (int k = 0; k < 5; ++k) {
    int id = k * 64 + l;
    uint32_t pk = (id < n) ? pts[(size_t)m * NPTS + id] : 0u;
    fx[k] = (float)(pk >> 16);
    fy[k] = (float)(pk & 0xFFFFu);
    if (id == 0 || id >= n) tmask |= 1 << k;
  }
  const float sx = __uint_as_float(
      (uint32_t)__builtin_amdgcn_readlane((int)__float_as_uint(fx[0]), 0));
  const float sy = __uint_as_float(
      (uint32_t)__builtin_amdgcn_readlane((int)__float_as_uint(fy[0]), 0));
#pragma unroll
  for (int k = 0; k < 5; ++k) {
    float dx = fx[k] - sx, dy = fy[k] - sy;
    md[k] = ((tmask >> k) & 1) ? INF : dx * dx + dy * dy;
  }

  float tp = 0.f;
  for (int it = 0; it < n - 1; ++it) {
    float lm = fminf(fminf(fminf(md[0], md[1]), fminf(md[2], md[3])), md[4]);
    const float minv = wave_min_f32_bcast(lm);  // uniform, always finite
    tp += minv;

    // locate one element achieving the min (dead lanes have INF, never match)
    bool c0 = (md[0] == minv), c1 = (md[1] == minv), c2 = (md[2] == minv);
    bool c3 = (md[3] == minv), c4 = (md[4] == minv);
    unsigned long long b0 = __ballot(c0), b1 = __ballot(c1);
    unsigned long long b2 = __ballot(c2), b3 = __ballot(c3);
    unsigned long long b4 = __ballot(c4);
    unsigned long long all = b0 | b1 | b2 | b3 | b4;
    const int L = __builtin_ctzll(all);  // winner lane (uniform)
    const int kslot = ((b0 >> L) & 1) ? 0
                    : ((b1 >> L) & 1) ? 1
                    : ((b2 >> L) & 1) ? 2
                    : ((b3 >> L) & 1) ? 3 : 4;  // winner slot (uniform)

    // winner coords: per-lane first-match select, read at lane L
    float wx = c0 ? fx[0] : c1 ? fx[1] : c2 ? fx[2] : c3 ? fx[3] : fx[4];
    float wy = c0 ? fy[0] : c1 ? fy[1] : c2 ? fy[2] : c3 ? fy[3] : fy[4];
    const float jx = __uint_as_float(
        (uint32_t)__builtin_amdgcn_readlane((int)__float_as_uint(wx), L));
    const float jy = __uint_as_float(
        (uint32_t)__builtin_amdgcn_readlane((int)__float_as_uint(wy), L));

    if (l == L) tmask |= 1 << kslot;  // mark winner dead BEFORE update

#pragma unroll
    for (int k = 0; k < 5; ++k) {
      float dx = fx[k] - jx, dy = fy[k] - jy;
      float nd = dx * dx + dy * dy;
      md[k] = ((tmask >> k) & 1) ? INF : fminf(md[k], nd);
    }
  }
  if (l == 0) tps[m] = tp;
}

// ---------------------------------------------------------------------------
// K4: loss = 1e-5 * sum_b |tp_mask - tp_pred| / 32
// ---------------------------------------------------------------------------
__global__ void finalize_kernel(const float* __restrict__ tps,
                                float* __restrict__ out) {
  const int tid = threadIdx.x;
  float v = 0.f;
  if (tid < 32) v = fabsf(tps[2 * tid + 1] - tps[2 * tid]);
#pragma unroll
  for (int off = 32; off > 0; off >>= 1) v += __shfl_xor(v, off, 64);
  if (tid == 0) out[0] = 1e-5f * v / 32.f;
}

// ---------------------------------------------------------------------------
extern "C" void kernel_launch(void* const* d_in, const int* in_sizes, int n_in,
                              void* d_out, int out_size, void* d_ws,
                              size_t ws_size, hipStream_t stream) {
  const float* mo = (const float*)d_in[0];
  const float* lb = (const float*)d_in[1];
  float* out = (float*)d_out;
  char* ws = (char*)d_ws;

  // ws layout (~3.4 MB):
  unsigned long long* bitmap = (unsigned long long*)ws;            // 2 MB
  unsigned int* gcnt   = (unsigned int*)(ws + 2097408);            // 256 B
  unsigned int* nsel   = (unsigned int*)(ws + 2097664);            // 256 B
  float* tps           = (float*)(ws + 2097920);                   // 256 B
  uint32_t* pts        = (uint32_t*)(ws + 2098176);                // 75 KB
  unsigned long long* cand = (unsigned long long*)(ws + 2251776);  // 1 MB
  unsigned int* wcnts  = (unsigned int*)(ws + 3300352);            // 32 KB

  edge_mask_kernel<<<dim3(32, 64), 256, 0, stream>>>(mo, lb, bitmap, wcnts,
                                                     gcnt);
  collect_kernel<<<dim3(16, 64), 256, 0, stream>>>(bitmap, wcnts, cand, gcnt);
  select_kernel<<<NMAPS, 256, 0, stream>>>(bitmap, wcnts, cand, gcnt, pts,
                                           nsel);
  mst_kernel<<<NMAPS, 64, 0, stream>>>(pts, nsel, tps);
  finalize_kernel<<<1, 64, 0, stream>>>(tps, out);
}

// Round 10
// 253.855 us; speedup vs baseline: 1.0983x; 1.0983x over previous
//
#include <hip/hip_runtime.h>
#include <cstdint>
#include <cstddef>

#define NPIX (512 * 512)
#define NMAPS 64
#define NPTS 300
#define CAP 2048          // global candidate cap per map (expect ~1300)
#define LCAP 640          // per-block LDS candidate cap (mean ~47)
#define NWORDS 4096       // 262144 bits / 64
#define TARGET 700.0      // fallback rescan target
// Fixed survivor threshold: keep-rate 1500/262144 (N-independent, so score
// can be computed at edge time). Survivors >= 300 whp for any N >~ 55K;
// select's exact bitmap-rescan fallback covers the rest unconditionally.
#define MT_FIXED 8340608u  // 8388608 - 32*1500

__device__ __forceinline__ uint32_t umin32(uint32_t a, uint32_t b) {
  return a < b ? a : b;
}

// ---------------------------------------------------------------------------
// Threefry-2x32, 20 rounds (exactly JAX's formulation).
// ---------------------------------------------------------------------------
__device__ __forceinline__ void tf2x32(uint32_t k0, uint32_t k1,
                                       uint32_t x0, uint32_t x1,
                                       uint32_t& o0, uint32_t& o1) {
  uint32_t ks2 = k0 ^ k1 ^ 0x1BD11BDAu;
#define TFR(r) { x0 += x1; x1 = (x1 << (r)) | (x1 >> (32 - (r))); x1 ^= x0; }
  x0 += k0; x1 += k1;
  TFR(13) TFR(15) TFR(26) TFR(6)
  x0 += k1; x1 += ks2 + 1u;
  TFR(17) TFR(29) TFR(16) TFR(24)
  x0 += ks2; x1 += k0 + 2u;
  TFR(13) TFR(15) TFR(26) TFR(6)
  x0 += k0; x1 += k1 + 3u;
  TFR(17) TFR(29) TFR(16) TFR(24)
  x0 += k1; x1 += ks2 + 4u;
  TFR(13) TFR(15) TFR(26) TFR(6)
  x0 += ks2; x1 += k0 + 5u;
#undef TFR
  o0 = x0; o1 = x1;
}

// partitionable threefry: bits at flat pixel p = o0^o1 of block (0,p);
// uniform f32 keeps mantissa bits>>9 (monotone) — compare as 23-bit ints.
__device__ __forceinline__ uint32_t score23(uint32_t k0, uint32_t k1, uint32_t p) {
  uint32_t a, b;
  tf2x32(k0, k1, 0u, p, a, b);
  return (a ^ b) >> 9;
}

__device__ __forceinline__ void map_key(int m, uint32_t& k0, uint32_t& k1) {
  tf2x32(0u, 42u, 0u, (uint32_t)m, k0, k1);  // split(key(42),64)[m]
}

// DPP helper (validated ctrl constants; CTRL must be an ICE -> template).
template <int CTRL>
__device__ __forceinline__ uint32_t dpp_mov_u32(uint32_t x) {
  return (uint32_t)__builtin_amdgcn_update_dpp((int)x, (int)x, CTRL, 0xF, 0xF,
                                               false);
}

// wave-64 u32 min reduction (HW-validated rounds 4/5, absmax 0).
__device__ __forceinline__ uint32_t wave_min_u32_bcast(uint32_t v) {
  v = umin32(v, dpp_mov_u32<0x111>(v));  // row_shr:1
  v = umin32(v, dpp_mov_u32<0x112>(v));  // row_shr:2
  v = umin32(v, dpp_mov_u32<0x114>(v));  // row_shr:4
  v = umin32(v, dpp_mov_u32<0x118>(v));  // row_shr:8
  v = umin32(v, dpp_mov_u32<0x142>(v));  // row_bcast:15
  v = umin32(v, dpp_mov_u32<0x143>(v));  // row_bcast:31
  return (uint32_t)__builtin_amdgcn_readlane((int)v, 63);
}

// ---------------------------------------------------------------------------
// K1: FUSED wave-rolling Sobel + threefry scoring + candidate collection.
// One wave owns a 64x32 strip; rows roll through registers; neighbors via
// __shfl (validated); ballot IS the bitmap word (kept for select's exact
// fallback). Each set-bit lane computes its threefry score inline; survivors
// (score >= MT_FIXED) append to LDS, flushed with one padded global atomic
// per block. Eliminates the whole collect kernel + bitmap re-read.
// ---------------------------------------------------------------------------
__global__ __launch_bounds__(256) void edge_collect_kernel(
    const float* __restrict__ mo, const float* __restrict__ lb,
    unsigned long long* __restrict__ bitmap, unsigned int* __restrict__ wcnts,
    unsigned long long* __restrict__ cand, unsigned int* __restrict__ gcnt32) {
  const int m = blockIdx.y;
  const int which = m & 1;
  const float* __restrict__ src = (which ? lb : mo) + (size_t)(m >> 1) * NPIX;
  const int l = threadIdx.x & 63;
  const int wi = blockIdx.x * 4 + (threadIdx.x >> 6);  // [0,128)
  const int cs = wi & 7;        // column strip
  const int seg = wi >> 3;      // row segment
  const int y0 = seg * 32;
  const int X = cs * 64 + l;
  const int hcol = (l == 0) ? X - 1 : ((l == 63) ? X + 1 : -1);

  __shared__ unsigned long long lbuf[LCAP];
  __shared__ unsigned int lcnt;
  __shared__ unsigned int lbase;
  if (threadIdx.x == 0) lcnt = 0;
  __syncthreads();

  uint32_t k0, k1;
  map_key(m, k0, k1);

  auto sig = [&](float t) { return which ? t : 1.f / (1.f + expf(-t)); };
  auto ldmain = [&](int row) -> float {
    return ((unsigned)row < 512u) ? sig(src[row * 512 + X]) : 0.f;
  };
  auto ldhalo = [&](int row) -> float {
    return ((unsigned)row < 512u && (unsigned)hcol < 512u)
               ? sig(src[row * 512 + hcol]) : 0.f;
  };

  float a = ldmain(y0 - 1), ha = ldhalo(y0 - 1);
  float b = ldmain(y0),     hb = ldhalo(y0);
  unsigned int cnt = 0;

  for (int i = 0; i < 32; ++i) {
    const int y = y0 + i;
    float c = ldmain(y + 1), hc = ldhalo(y + 1);

    // ha holds LEFT halo in lane 0 and RIGHT halo in lane 63.
    float aL = __shfl_up(a, 1);   if (l == 0)  aL = ha;
    float aR = __shfl_down(a, 1); if (l == 63) aR = ha;
    float bL = __shfl_up(b, 1);   if (l == 0)  bL = hb;
    float bR = __shfl_down(b, 1); if (l == 63) bR = hb;
    float cL = __shfl_up(c, 1);   if (l == 0)  cL = hc;
    float cR = __shfl_down(c, 1); if (l == 63) cR = hc;

    float ex = (aR - aL) + 2.f * (bR - bL) + (cR - cL);
    float ey = (cL + 2.f * c + cR) - (aL + 2.f * a + aR);
    float edge = sqrtf(ex * ex + ey * ey);
    bool bit = edge > 0.5f;

    unsigned long long ball = __ballot(bit);
    if (l == 0) {
      bitmap[(size_t)m * NWORDS + (size_t)y * 8 + cs] = ball;
      cnt += (unsigned int)__popcll(ball);
    }
    if (bit) {
      uint32_t p = (uint32_t)(y * 512 + X);
      uint32_t sc = score23(k0, k1, p);
      if (sc >= MT_FIXED) {
        unsigned int pos = atomicAdd(&lcnt, 1u);
        if (pos < LCAP)
          lbuf[pos] = ((unsigned long long)sc << 32) | (uint32_t)(~p);
      }
    }
    a = b; ha = hb; b = c; hb = hc;
  }
  if (l == 0) wcnts[m * 128 + wi] = cnt;

  __syncthreads();
  unsigned int cc = lcnt < LCAP ? lcnt : LCAP;
  if (threadIdx.x == 0)
    lbase = atomicAdd(&gcnt32[m * 32], lcnt + (lcnt > LCAP ? 0x1000000u : 0u));
  __syncthreads();
  for (unsigned int i = threadIdx.x; i < cc; i += 256) {
    unsigned int pos = lbase + i;
    if (pos < CAP) cand[(size_t)m * CAP + pos] = lbuf[i];
  }
}

// block-level N = sum of the 128 per-wave counts (wave 0 does it; result in
// LDS). Callers must __syncthreads() after.
__device__ __forceinline__ void reduce_N(const unsigned int* __restrict__ wcnts,
                                         int m, int tid, unsigned int* sN) {
  if (tid < 64) {
    unsigned int v = wcnts[m * 128 + tid] + wcnts[m * 128 + 64 + tid];
#pragma unroll
    for (int off = 32; off > 0; off >>= 1) v += __shfl_xor(v, off, 64);
    if (tid == 0) *sN = v;
  }
}

// ---------------------------------------------------------------------------
// K2: radix-SELECT (only the top-`need` SET matters; MST is order/start
// invariant). Fallback exact rescan if collection overflowed/short (covers
// the small-N case where MT_FIXED keeps < need survivors).
// ---------------------------------------------------------------------------
__global__ __launch_bounds__(256) void select_kernel(
    const unsigned long long* __restrict__ bitmap,
    const unsigned int* __restrict__ wcnts,
    const unsigned long long* __restrict__ cand,
    const unsigned int* __restrict__ gcnt32,
    uint32_t* __restrict__ pts, unsigned int* __restrict__ nsel) {
  const int m = blockIdx.x;
  const int tid = threadIdx.x;
  __shared__ unsigned long long buf[CAP];
  __shared__ unsigned int hist[256];
  __shared__ unsigned int s_tot, s_cnt, s_b, s_rank, sN;

  reduce_N(wcnts, m, tid, &sN);
  __syncthreads();
  const unsigned int N = sN;
  if (N == 0) { if (tid == 0) nsel[m] = 0; return; }
  const unsigned int need = N < NPTS ? N : NPTS;

  unsigned int c;
  const unsigned int g = gcnt32[m * 32];
  if (g >= need && g <= CAP) {
    c = g;
    for (unsigned int i = tid; i < c; i += 256)
      buf[i] = cand[(size_t)m * CAP + i];
    __syncthreads();
  } else {
    // fallback: exact iterative rescan of the bitmap
    uint32_t k0, k1;
    map_key(m, k0, k1);
    const unsigned long long* __restrict__ wmap = bitmap + (size_t)m * NWORDS;
    unsigned int mt = 0, cnt = 0;
    double target = TARGET;
    for (int iter = 0; iter < 16; ++iter) {
      mt = ((double)N > target)
               ? (unsigned int)(8388608.0 * (1.0 - target / (double)N))
               : 0u;
      if (tid == 0) s_tot = 0;
      __syncthreads();
      unsigned int lc = 0;
      for (int w = tid; w < NWORDS; w += 256) {
        unsigned long long word = wmap[w];
        while (word) {
          int bpos = __builtin_ctzll(word);
          word &= word - 1;
          uint32_t p = ((uint32_t)w << 6) + (uint32_t)bpos;
          lc += (score23(k0, k1, p) >= mt) ? 1u : 0u;
        }
      }
      if (lc) atomicAdd(&s_tot, lc);
      __syncthreads();
      cnt = s_tot;
      __syncthreads();
      if (cnt >= need && cnt <= CAP) break;
      if (cnt < need) target *= 3.0; else target *= 0.5;
    }
    if (tid == 0) s_cnt = 0;
    __syncthreads();
    for (int w = tid; w < NWORDS; w += 256) {
      unsigned long long word = wmap[w];
      while (word) {
        int bpos = __builtin_ctzll(word);
        word &= word - 1;
        uint32_t p = ((uint32_t)w << 6) + (uint32_t)bpos;
        uint32_t sc = score23(k0, k1, p);
        if (sc >= mt) {
          unsigned int pos = atomicAdd(&s_cnt, 1u);
          if (pos < CAP)
            buf[pos] = ((unsigned long long)sc << 32) | (uint32_t)(~p);
        }
      }
    }
    __syncthreads();
    c = s_cnt < CAP ? s_cnt : CAP;
    __syncthreads();
  }

  unsigned long long T = 0ull;
  if (c > need) {
    unsigned int rank = need;
    unsigned long long prefix = 0ull;
    for (int sh = 48; sh >= 0; sh -= 8) {
      hist[tid] = 0;
      __syncthreads();
      for (unsigned int i = tid; i < c; i += 256) {
        unsigned long long k = buf[i];
        if ((k >> (sh + 8)) == (prefix >> (sh + 8)))
          atomicAdd(&hist[(unsigned int)(k >> sh) & 255u], 1u);
      }
      __syncthreads();
      if (tid < 64) {
        unsigned int h0 = hist[4 * tid], h1 = hist[4 * tid + 1];
        unsigned int h2 = hist[4 * tid + 2], h3 = hist[4 * tid + 3];
        unsigned int gsum = h0 + h1 + h2 + h3;
        unsigned int s = gsum;
#pragma unroll
        for (int off = 1; off < 64; off <<= 1) {
          unsigned int o = __shfl_down(s, off, 64);
          s += (tid + off < 64) ? o : 0u;
        }
        unsigned int above = s - gsum;  // strictly higher digits
        unsigned int S3 = above, S2 = S3 + h3, S1 = S2 + h2, S0 = S1 + h1;
        if (S3 < rank && rank <= S3 + h3) { s_b = 4 * tid + 3; s_rank = rank - S3; }
        if (S2 < rank && rank <= S2 + h2) { s_b = 4 * tid + 2; s_rank = rank - S2; }
        if (S1 < rank && rank <= S1 + h1) { s_b = 4 * tid + 1; s_rank = rank - S1; }
        if (S0 < rank && rank <= S0 + h0) { s_b = 4 * tid + 0; s_rank = rank - S0; }
      }
      __syncthreads();
      prefix |= ((unsigned long long)s_b) << sh;
      rank = s_rank;
    }
    T = prefix;  // exact need-th largest key
  }

  if (tid == 0) s_cnt = 0;
  __syncthreads();
  for (unsigned int i = tid; i < c; i += 256) {
    unsigned long long k = buf[i];
    if (k >= T) {
      unsigned int pos = atomicAdd(&s_cnt, 1u);
      if (pos < NPTS) {
        uint32_t p = ~(uint32_t)k;
        pts[(size_t)m * NPTS + pos] = ((p >> 9) << 16) | (p & 511u);
      }
    }
  }
  __syncthreads();
  if (tid == 0) nsel[m] = s_cnt < need ? s_cnt : need;
}

// ---------------------------------------------------------------------------
// K3: Prim MST — the round-5-VALIDATED int version (85 us, absmax 0), with
// exactly one diff: __mul24 for the d2 products (coords < 512 => |dx| < 512,
// exact in i24; forces full-rate v_mad_i32_i24 instead of quarter-rate
// v_mul_lo_u32). Frontier key = (d2<<9 | id) in one u32; DPP argmin; dead
// slots pinned at 0xFFFFFFFF; winner removed by (ko,lo) compare.
// ---------------------------------------------------------------------------
__global__ __launch_bounds__(64, 1) void mst_kernel(
    const uint32_t* __restrict__ pts, const unsigned int* __restrict__ nsel,
    float* __restrict__ tps) {
  const int m = blockIdx.x;
  const int l = threadIdx.x;
  const int n = (int)nsel[m];
  if (n <= 1) { if (l == 0) tps[m] = 0.f; return; }

  uint32_t pk[5], key[5];
  int px[5], py[5];
#pragma unroll
  for (int k = 0; k < 5; ++k) {
    int id = k * 64 + l;
    pk[k] = (id < n) ? pts[(size_t)m * NPTS + id] : 0u;
  }
  const uint32_t p0 = (uint32_t)__builtin_amdgcn_readlane((int)pk[0], 0);
  const int x0 = (int)(p0 >> 16), y0 = (int)(p0 & 0xFFFFu);
#pragma unroll
  for (int k = 0; k < 5; ++k) {
    int id = k * 64 + l;
    px[k] = (int)(pk[k] >> 16);
    py[k] = (int)(pk[k] & 0xFFFFu);
    if (id > 0 && id < n) {
      int dx = px[k] - x0, dy = py[k] - y0;
      key[k] = ((uint32_t)(__mul24(dx, dx) + __mul24(dy, dy)) << 9) |
               (uint32_t)id;
    } else {
      key[k] = 0xFFFFFFFFu;
    }
  }

  float tp = 0.f;
  for (int it = 0; it < n - 1; ++it) {
    uint32_t best = umin32(umin32(umin32(key[0], key[1]),
                                  umin32(key[2], key[3])), key[4]);
    best = wave_min_u32_bcast(best);  // uniform across wave
    tp += (float)(best >> 9);         // exact: d2 < 2^19
    const int j = (int)(best & 511u);
    const int ko = j >> 6, lo = j & 63;
    uint32_t cp = pk[0];
#pragma unroll
    for (int k = 1; k < 5; ++k) cp = (ko == k) ? pk[k] : cp;
    const uint32_t pj = (uint32_t)__builtin_amdgcn_readlane((int)cp, lo);
    const int jx = (int)(pj >> 16), jy = (int)(pj & 0xFFFFu);
#pragma unroll
    for (int k = 0; k < 5; ++k) {
      int dx = px[k] - jx, dy = py[k] - jy;
      uint32_t nk = ((uint32_t)(__mul24(dx, dx) + __mul24(dy, dy)) << 9) |
                    (uint32_t)(k * 64 + l);
      uint32_t upd = (key[k] == 0xFFFFFFFFu) ? 0xFFFFFFFFu : umin32(key[k], nk);
      key[k] = (k == ko && l == lo) ? 0xFFFFFFFFu : upd;
    }
  }
  if (l == 0) tps[m] = tp;
}

// ---------------------------------------------------------------------------
// K4: loss = 1e-5 * sum_b |tp_mask - tp_pred| / 32
// ---------------------------------------------------------------------------
__global__ void finalize_kernel(const float* __restrict__ tps,
                                float* __restrict__ out) {
  const int tid = threadIdx.x;
  float v = 0.f;
  if (tid < 32) v = fabsf(tps[2 * tid + 1] - tps[2 * tid]);
#pragma unroll
  for (int off = 32; off > 0; off >>= 1) v += __shfl_xor(v, off, 64);
  if (tid == 0) out[0] = 1e-5f * v / 32.f;
}

// ---------------------------------------------------------------------------
extern "C" void kernel_launch(void* const* d_in, const int* in_sizes, int n_in,
                              void* d_out, int out_size, void* d_ws,
                              size_t ws_size, hipStream_t stream) {
  const float* mo = (const float*)d_in[0];
  const float* lb = (const float*)d_in[1];
  float* out = (float*)d_out;
  char* ws = (char*)d_ws;

  // ws layout (~3.27 MB):
  unsigned long long* bitmap = (unsigned long long*)ws;            // 2 MB
  unsigned long long* cand = (unsigned long long*)(ws + 2097152);  // 1 MB
  unsigned int* wcnts  = (unsigned int*)(ws + 3145728);            // 32 KB
  unsigned int* gcnt32 = (unsigned int*)(ws + 3178496);            // 8 KB (padded 128B/ctr)
  unsigned int* nsel   = (unsigned int*)(ws + 3186688);            // 256 B
  float* tps           = (float*)(ws + 3186944);                   // 256 B
  uint32_t* pts        = (uint32_t*)(ws + 3187200);                // 75 KB

  hipMemsetAsync(gcnt32, 0, 8192, stream);
  edge_collect_kernel<<<dim3(32, 64), 256, 0, stream>>>(mo, lb, bitmap, wcnts,
                                                        cand, gcnt32);
  select_kernel<<<NMAPS, 256, 0, stream>>>(bitmap, wcnts, cand, gcnt32, pts,
                                           nsel);
  mst_kernel<<<NMAPS, 64, 0, stream>>>(pts, nsel, tps);
  finalize_kernel<<<1, 64, 0, stream>>>(tps, out);
}

// Round 11
// 246.811 us; speedup vs baseline: 1.1296x; 1.0285x over previous
//
#include <hip/hip_runtime.h>
#include <cstdint>
#include <cstddef>

#define NPIX (512 * 512)
#define NMAPS 64
#define NPTS 300
#define CAP 1024          // global candidate cap per map (E~620, +16 sigma)
#define LCAP 640          // per-block LDS candidate cap (E~20)
#define NWORDS 4096       // 262144 bits / 64
#define TARGET 700.0      // fallback rescan target
// Fixed survivor threshold: keep-rate 20000/2^23 ~= 0.238%. N ~= 260K/map
// (measured r10: ~all pixels pass edge>0.5) => E ~= 620 survivors, 12+ sigma
// above need=300. Select's exact bitmap-rescan fallback covers any shortfall.
#define MT_FIXED 8368608u  // 8388608 - 20000

__device__ __forceinline__ uint32_t umin32(uint32_t a, uint32_t b) {
  return a < b ? a : b;
}

// ---------------------------------------------------------------------------
// Threefry-2x32, 20 rounds (exactly JAX's formulation).
// ---------------------------------------------------------------------------
__device__ __forceinline__ void tf2x32(uint32_t k0, uint32_t k1,
                                       uint32_t x0, uint32_t x1,
                                       uint32_t& o0, uint32_t& o1) {
  uint32_t ks2 = k0 ^ k1 ^ 0x1BD11BDAu;
#define TFR(r) { x0 += x1; x1 = (x1 << (r)) | (x1 >> (32 - (r))); x1 ^= x0; }
  x0 += k0; x1 += k1;
  TFR(13) TFR(15) TFR(26) TFR(6)
  x0 += k1; x1 += ks2 + 1u;
  TFR(17) TFR(29) TFR(16) TFR(24)
  x0 += ks2; x1 += k0 + 2u;
  TFR(13) TFR(15) TFR(26) TFR(6)
  x0 += k0; x1 += k1 + 3u;
  TFR(17) TFR(29) TFR(16) TFR(24)
  x0 += k1; x1 += ks2 + 4u;
  TFR(13) TFR(15) TFR(26) TFR(6)
  x0 += ks2; x1 += k0 + 5u;
#undef TFR
  o0 = x0; o1 = x1;
}

// partitionable threefry: bits at flat pixel p = o0^o1 of block (0,p);
// uniform f32 keeps mantissa bits>>9 (monotone) — compare as 23-bit ints.
__device__ __forceinline__ uint32_t score23(uint32_t k0, uint32_t k1, uint32_t p) {
  uint32_t a, b;
  tf2x32(k0, k1, 0u, p, a, b);
  return (a ^ b) >> 9;
}

__device__ __forceinline__ void map_key(int m, uint32_t& k0, uint32_t& k1) {
  tf2x32(0u, 42u, 0u, (uint32_t)m, k0, k1);  // split(key(42),64)[m]
}

// DPP helper (validated ctrl constants; CTRL must be an ICE -> template).
template <int CTRL>
__device__ __forceinline__ uint32_t dpp_mov_u32(uint32_t x) {
  return (uint32_t)__builtin_amdgcn_update_dpp((int)x, (int)x, CTRL, 0xF, 0xF,
                                               false);
}

// wave-64 u32 min reduction (HW-validated rounds 4/5, absmax 0).
__device__ __forceinline__ uint32_t wave_min_u32_bcast(uint32_t v) {
  v = umin32(v, dpp_mov_u32<0x111>(v));  // row_shr:1
  v = umin32(v, dpp_mov_u32<0x112>(v));  // row_shr:2
  v = umin32(v, dpp_mov_u32<0x114>(v));  // row_shr:4
  v = umin32(v, dpp_mov_u32<0x118>(v));  // row_shr:8
  v = umin32(v, dpp_mov_u32<0x142>(v));  // row_bcast:15
  v = umin32(v, dpp_mov_u32<0x143>(v));  // row_bcast:31
  return (uint32_t)__builtin_amdgcn_readlane((int)v, 63);
}

// ---------------------------------------------------------------------------
// K1: FUSED wave-rolling Sobel + threefry scoring + candidate collection.
// r11 VALU diet: __expf sigmoid (v_exp_f32, ~5 instrs vs ~18 libm) and
// squared-threshold (no v_sqrt). Boundary-ulp flips change <= a few selected
// points -> loss shift ~2e-5 << 1.1e-3 threshold. Block (0,0) zeroes out[0]
// for mst's fused finalize (kernel boundary orders it).
// ---------------------------------------------------------------------------
__global__ __launch_bounds__(256) void edge_collect_kernel(
    const float* __restrict__ mo, const float* __restrict__ lb,
    unsigned long long* __restrict__ bitmap, unsigned int* __restrict__ wcnts,
    unsigned long long* __restrict__ cand, unsigned int* __restrict__ gcnt32,
    float* __restrict__ out) {
  const int m = blockIdx.y;
  const int which = m & 1;
  const float* __restrict__ src = (which ? lb : mo) + (size_t)(m >> 1) * NPIX;
  const int l = threadIdx.x & 63;
  const int wi = blockIdx.x * 4 + (threadIdx.x >> 6);  // [0,128)
  const int cs = wi & 7;        // column strip
  const int seg = wi >> 3;      // row segment
  const int y0 = seg * 32;
  const int X = cs * 64 + l;
  const int hcol = (l == 0) ? X - 1 : ((l == 63) ? X + 1 : -1);

  if (m == 0 && blockIdx.x == 0 && threadIdx.x == 0) out[0] = 0.f;

  __shared__ unsigned long long lbuf[LCAP];
  __shared__ unsigned int lcnt;
  __shared__ unsigned int lbase;
  if (threadIdx.x == 0) lcnt = 0;
  __syncthreads();

  uint32_t k0, k1;
  map_key(m, k0, k1);

  auto sig = [&](float t) {
    return which ? t : 1.f / (1.f + __expf(-t));  // fast sigmoid
  };
  auto ldmain = [&](int row) -> float {
    return ((unsigned)row < 512u) ? sig(src[row * 512 + X]) : 0.f;
  };
  auto ldhalo = [&](int row) -> float {
    return ((unsigned)row < 512u && (unsigned)hcol < 512u)
               ? sig(src[row * 512 + hcol]) : 0.f;
  };

  float a = ldmain(y0 - 1), ha = ldhalo(y0 - 1);
  float b = ldmain(y0),     hb = ldhalo(y0);
  unsigned int cnt = 0;

  for (int i = 0; i < 32; ++i) {
    const int y = y0 + i;
    float c = ldmain(y + 1), hc = ldhalo(y + 1);

    // ha holds LEFT halo in lane 0 and RIGHT halo in lane 63.
    float aL = __shfl_up(a, 1);   if (l == 0)  aL = ha;
    float aR = __shfl_down(a, 1); if (l == 63) aR = ha;
    float bL = __shfl_up(b, 1);   if (l == 0)  bL = hb;
    float bR = __shfl_down(b, 1); if (l == 63) bR = hb;
    float cL = __shfl_up(c, 1);   if (l == 0)  cL = hc;
    float cR = __shfl_down(c, 1); if (l == 63) cR = hc;

    float ex = (aR - aL) + 2.f * (bR - bL) + (cR - cL);
    float ey = (cL + 2.f * c + cR) - (aL + 2.f * a + aR);
    bool bit = (ex * ex + ey * ey) > 0.25f;  // edge > 0.5, no sqrt

    unsigned long long ball = __ballot(bit);
    if (l == 0) {
      bitmap[(size_t)m * NWORDS + (size_t)y * 8 + cs] = ball;
      cnt += (unsigned int)__popcll(ball);
    }
    if (bit) {
      uint32_t p = (uint32_t)(y * 512 + X);
      uint32_t sc = score23(k0, k1, p);
      if (sc >= MT_FIXED) {
        unsigned int pos = atomicAdd(&lcnt, 1u);
        if (pos < LCAP)
          lbuf[pos] = ((unsigned long long)sc << 32) | (uint32_t)(~p);
      }
    }
    a = b; ha = hb; b = c; hb = hc;
  }
  if (l == 0) wcnts[m * 128 + wi] = cnt;

  __syncthreads();
  unsigned int cc = lcnt < LCAP ? lcnt : LCAP;
  if (threadIdx.x == 0)
    lbase = atomicAdd(&gcnt32[m * 32], lcnt + (lcnt > LCAP ? 0x1000000u : 0u));
  __syncthreads();
  for (unsigned int i = threadIdx.x; i < cc; i += 256) {
    unsigned int pos = lbase + i;
    if (pos < CAP) cand[(size_t)m * CAP + pos] = lbuf[i];
  }
}

// block-level N = sum of the 128 per-wave counts (wave 0 does it; result in
// LDS). Callers must __syncthreads() after.
__device__ __forceinline__ void reduce_N(const unsigned int* __restrict__ wcnts,
                                         int m, int tid, unsigned int* sN) {
  if (tid < 64) {
    unsigned int v = wcnts[m * 128 + tid] + wcnts[m * 128 + 64 + tid];
#pragma unroll
    for (int off = 32; off > 0; off >>= 1) v += __shfl_xor(v, off, 64);
    if (tid == 0) *sN = v;
  }
}

// ---------------------------------------------------------------------------
// K2: radix-SELECT (only the top-`need` SET matters; MST is order/start
// invariant). Fallback exact rescan if collection overflowed/short.
// ---------------------------------------------------------------------------
__global__ __launch_bounds__(256) void select_kernel(
    const unsigned long long* __restrict__ bitmap,
    const unsigned int* __restrict__ wcnts,
    const unsigned long long* __restrict__ cand,
    const unsigned int* __restrict__ gcnt32,
    uint32_t* __restrict__ pts, unsigned int* __restrict__ nsel) {
  const int m = blockIdx.x;
  const int tid = threadIdx.x;
  __shared__ unsigned long long buf[CAP];
  __shared__ unsigned int hist[256];
  __shared__ unsigned int s_tot, s_cnt, s_b, s_rank, sN;

  reduce_N(wcnts, m, tid, &sN);
  __syncthreads();
  const unsigned int N = sN;
  if (N == 0) { if (tid == 0) nsel[m] = 0; return; }
  const unsigned int need = N < NPTS ? N : NPTS;

  unsigned int c;
  const unsigned int g = gcnt32[m * 32];
  if (g >= need && g <= CAP) {
    c = g;
    for (unsigned int i = tid; i < c; i += 256)
      buf[i] = cand[(size_t)m * CAP + i];
    __syncthreads();
  } else {
    // fallback: exact iterative rescan of the bitmap
    uint32_t k0, k1;
    map_key(m, k0, k1);
    const unsigned long long* __restrict__ wmap = bitmap + (size_t)m * NWORDS;
    unsigned int mt = 0, cnt = 0;
    double target = TARGET;
    for (int iter = 0; iter < 16; ++iter) {
      mt = ((double)N > target)
               ? (unsigned int)(8388608.0 * (1.0 - target / (double)N))
               : 0u;
      if (tid == 0) s_tot = 0;
      __syncthreads();
      unsigned int lc = 0;
      for (int w = tid; w < NWORDS; w += 256) {
        unsigned long long word = wmap[w];
        while (word) {
          int bpos = __builtin_ctzll(word);
          word &= word - 1;
          uint32_t p = ((uint32_t)w << 6) + (uint32_t)bpos;
          lc += (score23(k0, k1, p) >= mt) ? 1u : 0u;
        }
      }
      if (lc) atomicAdd(&s_tot, lc);
      __syncthreads();
      cnt = s_tot;
      __syncthreads();
      if (cnt >= need && cnt <= CAP) break;
      if (cnt < need) target *= 3.0; else target *= 0.5;
    }
    if (tid == 0) s_cnt = 0;
    __syncthreads();
    for (int w = tid; w < NWORDS; w += 256) {
      unsigned long long word = wmap[w];
      while (word) {
        int bpos = __builtin_ctzll(word);
        word &= word - 1;
        uint32_t p = ((uint32_t)w << 6) + (uint32_t)bpos;
        uint32_t sc = score23(k0, k1, p);
        if (sc >= mt) {
          unsigned int pos = atomicAdd(&s_cnt, 1u);
          if (pos < CAP)
            buf[pos] = ((unsigned long long)sc << 32) | (uint32_t)(~p);
        }
      }
    }
    __syncthreads();
    c = s_cnt < CAP ? s_cnt : CAP;
    __syncthreads();
  }

  unsigned long long T = 0ull;
  if (c > need) {
    unsigned int rank = need;
    unsigned long long prefix = 0ull;
    for (int sh = 48; sh >= 0; sh -= 8) {
      hist[tid] = 0;
      __syncthreads();
      for (unsigned int i = tid; i < c; i += 256) {
        unsigned long long k = buf[i];
        if ((k >> (sh + 8)) == (prefix >> (sh + 8)))
          atomicAdd(&hist[(unsigned int)(k >> sh) & 255u], 1u);
      }
      __syncthreads();
      if (tid < 64) {
        unsigned int h0 = hist[4 * tid], h1 = hist[4 * tid + 1];
        unsigned int h2 = hist[4 * tid + 2], h3 = hist[4 * tid + 3];
        unsigned int gsum = h0 + h1 + h2 + h3;
        unsigned int s = gsum;
#pragma unroll
        for (int off = 1; off < 64; off <<= 1) {
          unsigned int o = __shfl_down(s, off, 64);
          s += (tid + off < 64) ? o : 0u;
        }
        unsigned int above = s - gsum;  // strictly higher digits
        unsigned int S3 = above, S2 = S3 + h3, S1 = S2 + h2, S0 = S1 + h1;
        if (S3 < rank && rank <= S3 + h3) { s_b = 4 * tid + 3; s_rank = rank - S3; }
        if (S2 < rank && rank <= S2 + h2) { s_b = 4 * tid + 2; s_rank = rank - S2; }
        if (S1 < rank && rank <= S1 + h1) { s_b = 4 * tid + 1; s_rank = rank - S1; }
        if (S0 < rank && rank <= S0 + h0) { s_b = 4 * tid + 0; s_rank = rank - S0; }
      }
      __syncthreads();
      prefix |= ((unsigned long long)s_b) << sh;
      rank = s_rank;
    }
    T = prefix;  // exact need-th largest key
  }

  if (tid == 0) s_cnt = 0;
  __syncthreads();
  for (unsigned int i = tid; i < c; i += 256) {
    unsigned long long k = buf[i];
    if (k >= T) {
      unsigned int pos = atomicAdd(&s_cnt, 1u);
      if (pos < NPTS) {
        uint32_t p = ~(uint32_t)k;
        pts[(size_t)m * NPTS + pos] = ((p >> 9) << 16) | (p & 511u);
      }
    }
  }
  __syncthreads();
  if (tid == 0) nsel[m] = s_cnt < need ? s_cnt : need;
}

// ---------------------------------------------------------------------------
// K3: Prim MST + FUSED finalize. One block = one batch pair; wave 0 runs
// map 2b (pred), wave 1 runs map 2b+1 (mask) — independent chains in
// parallel waves. Int d2 via __mul24 (exact, full-rate), u32 tp accumulation
// (exact: sum < 2^31), DPP argmin (validated). Block then atomicAdds
// 1e-5*|tp1-tp0|/32 into out[0] (zeroed by edge kernel).
// ---------------------------------------------------------------------------
__global__ __launch_bounds__(128, 1) void mst_kernel(
    const uint32_t* __restrict__ pts, const unsigned int* __restrict__ nsel,
    float* __restrict__ out) {
  const int wv = threadIdx.x >> 6;           // 0 = pred, 1 = mask
  const int m = blockIdx.x * 2 + wv;
  const int l = threadIdx.x & 63;
  const int n = (int)nsel[m];
  __shared__ float stp[2];

  unsigned int utp = 0;
  if (n > 1) {
    uint32_t pk[5], key[5];
    int px[5], py[5];
#pragma unroll
    for (int k = 0; k < 5; ++k) {
      int id = k * 64 + l;
      pk[k] = (id < n) ? pts[(size_t)m * NPTS + id] : 0u;
    }
    const uint32_t p0 = (uint32_t)__builtin_amdgcn_readlane((int)pk[0], 0);
    const int x0 = (int)(p0 >> 16), y0 = (int)(p0 & 0xFFFFu);
#pragma unroll
    for (int k = 0; k < 5; ++k) {
      int id = k * 64 + l;
      px[k] = (int)(pk[k] >> 16);
      py[k] = (int)(pk[k] & 0xFFFFu);
      if (id > 0 && id < n) {
        int dx = px[k] - x0, dy = py[k] - y0;
        key[k] = ((uint32_t)(__mul24(dx, dx) + __mul24(dy, dy)) << 9) |
                 (uint32_t)id;
      } else {
        key[k] = 0xFFFFFFFFu;
      }
    }

    for (int it = 0; it < n - 1; ++it) {
      uint32_t best = umin32(umin32(umin32(key[0], key[1]),
                                    umin32(key[2], key[3])), key[4]);
      best = wave_min_u32_bcast(best);  // uniform across wave
      utp += best >> 9;                 // exact: sum < 2^31
      const int j = (int)(best & 511u);
      const int ko = j >> 6, lo = j & 63;
      uint32_t cp = pk[0];
#pragma unroll
      for (int k = 1; k < 5; ++k) cp = (ko == k) ? pk[k] : cp;
      const uint32_t pj = (uint32_t)__builtin_amdgcn_readlane((int)cp, lo);
      const int jx = (int)(pj >> 16), jy = (int)(pj & 0xFFFFu);
#pragma unroll
      for (int k = 0; k < 5; ++k) {
        int dx = px[k] - jx, dy = py[k] - jy;
        uint32_t nk = ((uint32_t)(__mul24(dx, dx) + __mul24(dy, dy)) << 9) |
                      (uint32_t)(k * 64 + l);
        uint32_t upd =
            (key[k] == 0xFFFFFFFFu) ? 0xFFFFFFFFu : umin32(key[k], nk);
        key[k] = (k == ko && l == lo) ? 0xFFFFFFFFu : upd;
      }
    }
  }
  if (l == 0) stp[wv] = (float)utp;
  __syncthreads();
  if (threadIdx.x == 0)
    atomicAdd(out, 1e-5f * fabsf(stp[1] - stp[0]) / 32.f);
}

// ---------------------------------------------------------------------------
extern "C" void kernel_launch(void* const* d_in, const int* in_sizes, int n_in,
                              void* d_out, int out_size, void* d_ws,
                              size_t ws_size, hipStream_t stream) {
  const float* mo = (const float*)d_in[0];
  const float* lb = (const float*)d_in[1];
  float* out = (float*)d_out;
  char* ws = (char*)d_ws;

  // ws layout (~2.75 MB):
  unsigned long long* bitmap = (unsigned long long*)ws;            // 2 MB
  unsigned long long* cand = (unsigned long long*)(ws + 2097152);  // 512 KB
  unsigned int* wcnts  = (unsigned int*)(ws + 2621440);            // 32 KB
  unsigned int* gcnt32 = (unsigned int*)(ws + 2654208);            // 8 KB (padded 128B/ctr)
  unsigned int* nsel   = (unsigned int*)(ws + 2662400);            // 256 B
  uint32_t* pts        = (uint32_t*)(ws + 2662656);                // 75 KB

  hipMemsetAsync(gcnt32, 0, 8192, stream);
  edge_collect_kernel<<<dim3(32, 64), 256, 0, stream>>>(mo, lb, bitmap, wcnts,
                                                        cand, gcnt32, out);
  select_kernel<<<NMAPS, 256, 0, stream>>>(bitmap, wcnts, cand, gcnt32, pts,
                                           nsel);
  mst_kernel<<<32, 128, 0, stream>>>(pts, nsel, out);
}

// Round 12
// 238.660 us; speedup vs baseline: 1.1682x; 1.0342x over previous
//
#include <hip/hip_runtime.h>
#include <cstdint>
#include <cstddef>

#define NPIX (512 * 512)
#define NMAPS 64
#define NPTS 300
#define CAP 2048           // per-map candidate region (32 blocks x 64 slots)
#define SLOTS 64           // per-block candidate slots (E~19, 10 sigma safe)
#define LBUFSZ 256         // LDS staging for per-block survivors
#define NWORDS 4096        // 262144 bits / 64
#define TARGET 700.0       // fallback rescan target
// Fixed keep-rate 20000/2^23: E~620 survivors/map (N~260K measured r10).
// Compare raw threefry bits against MT<<9 (exactly equiv to score>=MT).
#define MT_BITS 0xFF63C000u  // (8388608-20000)<<9

__device__ __forceinline__ uint32_t umin32(uint32_t a, uint32_t b) {
  return a < b ? a : b;
}

// ---------------------------------------------------------------------------
// Threefry-2x32, 20 rounds (exactly JAX's formulation).
// ---------------------------------------------------------------------------
__device__ __forceinline__ void tf2x32(uint32_t k0, uint32_t k1,
                                       uint32_t x0, uint32_t x1,
                                       uint32_t& o0, uint32_t& o1) {
  uint32_t ks2 = k0 ^ k1 ^ 0x1BD11BDAu;
#define TFR(r) { x0 += x1; x1 = (x1 << (r)) | (x1 >> (32 - (r))); x1 ^= x0; }
  x0 += k0; x1 += k1;
  TFR(13) TFR(15) TFR(26) TFR(6)
  x0 += k1; x1 += ks2 + 1u;
  TFR(17) TFR(29) TFR(16) TFR(24)
  x0 += ks2; x1 += k0 + 2u;
  TFR(13) TFR(15) TFR(26) TFR(6)
  x0 += k0; x1 += k1 + 3u;
  TFR(17) TFR(29) TFR(16) TFR(24)
  x0 += k1; x1 += ks2 + 4u;
  TFR(13) TFR(15) TFR(26) TFR(6)
  x0 += ks2; x1 += k0 + 5u;
#undef TFR
  o0 = x0; o1 = x1;
}

__device__ __forceinline__ uint32_t score23(uint32_t k0, uint32_t k1, uint32_t p) {
  uint32_t a, b;
  tf2x32(k0, k1, 0u, p, a, b);
  return (a ^ b) >> 9;
}

__device__ __forceinline__ void map_key(int m, uint32_t& k0, uint32_t& k1) {
  tf2x32(0u, 42u, 0u, (uint32_t)m, k0, k1);  // split(key(42),64)[m]
}

// DPP helper (validated ctrl constants; CTRL must be an ICE -> template).
template <int CTRL>
__device__ __forceinline__ uint32_t dpp_mov_u32(uint32_t x) {
  return (uint32_t)__builtin_amdgcn_update_dpp((int)x, (int)x, CTRL, 0xF, 0xF,
                                               false);
}

// wave-64 u32 min reduction (HW-validated, absmax 0 across rounds).
__device__ __forceinline__ uint32_t wave_min_u32_bcast(uint32_t v) {
  v = umin32(v, dpp_mov_u32<0x111>(v));  // row_shr:1
  v = umin32(v, dpp_mov_u32<0x112>(v));  // row_shr:2
  v = umin32(v, dpp_mov_u32<0x114>(v));  // row_shr:4
  v = umin32(v, dpp_mov_u32<0x118>(v));  // row_shr:8
  v = umin32(v, dpp_mov_u32<0x142>(v));  // row_bcast:15
  v = umin32(v, dpp_mov_u32<0x143>(v));  // row_bcast:31
  return (uint32_t)__builtin_amdgcn_readlane((int)v, 63);
}

// ---------------------------------------------------------------------------
// K1 body: wave-rolling SEPARABLE Sobel (t=a+2b+c, u=c-a => 4 shfls not 6)
// + inline threefry survivor test. Templated: PRED = apply sigmoid
// (model_output maps only), YIN = strip has no y-boundary (segs 1..14).
// ---------------------------------------------------------------------------
template <bool PRED, bool YIN>
__device__ __forceinline__ void edge_body(
    const float* __restrict__ src, unsigned long long* __restrict__ bitmap,
    unsigned int* __restrict__ wcnts, unsigned long long* lbuf,
    unsigned int* lcnt, int m, int l, int cs, int seg, int wi, uint32_t k0,
    uint32_t k1) {
  const int y0 = seg * 32;
  const int X = cs * 64 + l;
  const int hcol = (l == 0) ? X - 1 : ((l == 63) ? X + 1 : -1);
  const bool hok = (unsigned)hcol < 512u;

  auto val = [&](float t) -> float {
    if constexpr (PRED) return 1.f / (1.f + __expf(-t));
    else return t;
  };
  auto ldm = [&](int row) -> float {
    if constexpr (!YIN) {
      if ((unsigned)row >= 512u) return 0.f;
    }
    return val(src[row * 512 + X]);
  };
  auto ldh = [&](int row) -> float {
    if (!hok) return 0.f;
    if constexpr (!YIN) {
      if ((unsigned)row >= 512u) return 0.f;
    }
    return val(src[row * 512 + hcol]);
  };

  float a = ldm(y0 - 1), b = ldm(y0);
  float ha = ldh(y0 - 1), hb = ldh(y0);
  unsigned int cnt = 0;

  for (int i = 0; i < 32; ++i) {
    const int y = y0 + i;
    float c = ldm(y + 1), hc = ldh(y + 1);

    float t = a + 2.f * b + c;   // vertical [1,2,1]
    float u = c - a;             // vertical [-1,0,1]
    float th = ha + 2.f * hb + hc;
    float uh = hc - ha;

    float tL = __shfl_up(t, 1);   if (l == 0)  tL = th;
    float tR = __shfl_down(t, 1); if (l == 63) tR = th;
    float uL = __shfl_up(u, 1);   if (l == 0)  uL = uh;
    float uR = __shfl_down(u, 1); if (l == 63) uR = uh;

    float ex = tR - tL;
    float ey = uL + 2.f * u + uR;
    bool bit = (ex * ex + ey * ey) > 0.25f;  // edge > 0.5

    unsigned long long ball = __ballot(bit);
    if (l == 0) {
      bitmap[(size_t)m * NWORDS + (size_t)y * 8 + cs] = ball;
      cnt += (unsigned int)__popcll(ball);
    }
    if (bit) {
      uint32_t p = (uint32_t)(y * 512 + X);
      uint32_t o0, o1;
      tf2x32(k0, k1, 0u, p, o0, o1);
      uint32_t x = o0 ^ o1;
      if (x >= MT_BITS) {
        unsigned int pos = atomicAdd(lcnt, 1u);
        if (pos < LBUFSZ)
          lbuf[pos] = ((unsigned long long)(x >> 9) << 32) | (uint32_t)(~p);
      }
    }
    a = b; b = c; ha = hb; hb = hc;
  }
  if (l == 0) wcnts[m * 128 + wi] = cnt;
}

// ---------------------------------------------------------------------------
// K1: fused Sobel+threefry+collect. Per-BLOCK candidate slots (no global
// atomics, no memset): block bx writes up to 64 survivors at its own offset
// and always stores its raw count to bcnt. seg/which are block-uniform, so
// the template dispatch below is branch-cheap.
// ---------------------------------------------------------------------------
__global__ __launch_bounds__(256) void edge_collect_kernel(
    const float* __restrict__ mo, const float* __restrict__ lb,
    unsigned long long* __restrict__ bitmap, unsigned int* __restrict__ wcnts,
    unsigned long long* __restrict__ cand, unsigned int* __restrict__ bcnt,
    float* __restrict__ out) {
  const int m = blockIdx.y;
  const int which = m & 1;
  const int bx = blockIdx.x;
  const float* __restrict__ src = (which ? lb : mo) + (size_t)(m >> 1) * NPIX;
  const int l = threadIdx.x & 63;
  const int wi = bx * 4 + (threadIdx.x >> 6);  // [0,128)
  const int cs = wi & 7;
  const int seg = wi >> 3;  // uniform across the block's 4 waves

  if (m == 0 && bx == 0 && threadIdx.x == 0) out[0] = 0.f;

  __shared__ unsigned long long lbuf[LBUFSZ];
  __shared__ unsigned int lcnt;
  if (threadIdx.x == 0) lcnt = 0;
  __syncthreads();

  uint32_t k0, k1;
  map_key(m, k0, k1);

  const bool yin = (seg != 0) && (seg != 15);
  if (which) {
    if (yin) edge_body<false, true>(src, bitmap, wcnts, lbuf, &lcnt, m, l, cs, seg, wi, k0, k1);
    else     edge_body<false, false>(src, bitmap, wcnts, lbuf, &lcnt, m, l, cs, seg, wi, k0, k1);
  } else {
    if (yin) edge_body<true, true>(src, bitmap, wcnts, lbuf, &lcnt, m, l, cs, seg, wi, k0, k1);
    else     edge_body<true, false>(src, bitmap, wcnts, lbuf, &lcnt, m, l, cs, seg, wi, k0, k1);
  }

  __syncthreads();
  const unsigned int total = lcnt;
  const unsigned int cc = total < SLOTS ? total : SLOTS;
  for (unsigned int i = threadIdx.x; i < cc; i += 256)
    cand[(size_t)m * CAP + bx * SLOTS + i] = lbuf[i];
  if (threadIdx.x == 0) bcnt[m * 32 + bx] = total;
}

// block-level N = sum of the 128 per-wave counts.
__device__ __forceinline__ void reduce_N(const unsigned int* __restrict__ wcnts,
                                         int m, int tid, unsigned int* sN) {
  if (tid < 64) {
    unsigned int v = wcnts[m * 128 + tid] + wcnts[m * 128 + 64 + tid];
#pragma unroll
    for (int off = 32; off > 0; off >>= 1) v += __shfl_xor(v, off, 64);
    if (tid == 0) *sN = v;
  }
}

// ---------------------------------------------------------------------------
// K2: compact per-block slots -> radix-SELECT top-`need` set. Fallback exact
// bitmap rescan on overflow/shortfall (correctness unconditional).
// ---------------------------------------------------------------------------
__global__ __launch_bounds__(256) void select_kernel(
    const unsigned long long* __restrict__ bitmap,
    const unsigned int* __restrict__ wcnts,
    const unsigned long long* __restrict__ cand,
    const unsigned int* __restrict__ bcnt,
    uint32_t* __restrict__ pts, unsigned int* __restrict__ nsel) {
  const int m = blockIdx.x;
  const int tid = threadIdx.x;
  __shared__ unsigned long long buf[CAP];
  __shared__ unsigned int hist[256];
  __shared__ unsigned int scnt32[32];
  __shared__ unsigned int sbase[33];
  __shared__ unsigned int s_tot, s_cnt, s_b, s_rank, sN, s_ovf;

  reduce_N(wcnts, m, tid, &sN);
  if (tid < 32) scnt32[tid] = bcnt[m * 32 + tid];
  __syncthreads();
  const unsigned int N = sN;
  if (N == 0) { if (tid == 0) nsel[m] = 0; return; }
  const unsigned int need = N < NPTS ? N : NPTS;

  if (tid == 0) {
    unsigned int s = 0, ovf = 0;
    for (int i = 0; i < 32; ++i) {
      sbase[i] = s;
      unsigned int cg = scnt32[i];
      if (cg > SLOTS) ovf = 1;
      s += cg < SLOTS ? cg : SLOTS;
    }
    sbase[32] = s;
    s_ovf = ovf;
  }
  __syncthreads();

  unsigned int c;
  if (!s_ovf && sbase[32] >= need) {
    c = sbase[32];
    const int g = tid >> 3, j0 = tid & 7;  // 32 groups x 8 threads
    const unsigned int cg = scnt32[g] < SLOTS ? scnt32[g] : SLOTS;
    for (unsigned int i = j0; i < cg; i += 8)
      buf[sbase[g] + i] = cand[(size_t)m * CAP + g * SLOTS + i];
    __syncthreads();
  } else {
    // fallback: exact iterative rescan of the bitmap
    uint32_t k0, k1;
    map_key(m, k0, k1);
    const unsigned long long* __restrict__ wmap = bitmap + (size_t)m * NWORDS;
    unsigned int mt = 0, cnt = 0;
    double target = TARGET;
    for (int iter = 0; iter < 16; ++iter) {
      mt = ((double)N > target)
               ? (unsigned int)(8388608.0 * (1.0 - target / (double)N))
               : 0u;
      if (tid == 0) s_tot = 0;
      __syncthreads();
      unsigned int lc = 0;
      for (int w = tid; w < NWORDS; w += 256) {
        unsigned long long word = wmap[w];
        while (word) {
          int bpos = __builtin_ctzll(word);
          word &= word - 1;
          uint32_t p = ((uint32_t)w << 6) + (uint32_t)bpos;
          lc += (score23(k0, k1, p) >= mt) ? 1u : 0u;
        }
      }
      if (lc) atomicAdd(&s_tot, lc);
      __syncthreads();
      cnt = s_tot;
      __syncthreads();
      if (cnt >= need && cnt <= CAP) break;
      if (cnt < need) target *= 3.0; else target *= 0.5;
    }
    if (tid == 0) s_cnt = 0;
    __syncthreads();
    for (int w = tid; w < NWORDS; w += 256) {
      unsigned long long word = wmap[w];
      while (word) {
        int bpos = __builtin_ctzll(word);
        word &= word - 1;
        uint32_t p = ((uint32_t)w << 6) + (uint32_t)bpos;
        uint32_t sc = score23(k0, k1, p);
        if (sc >= mt) {
          unsigned int pos = atomicAdd(&s_cnt, 1u);
          if (pos < CAP)
            buf[pos] = ((unsigned long long)sc << 32) | (uint32_t)(~p);
        }
      }
    }
    __syncthreads();
    c = s_cnt < CAP ? s_cnt : CAP;
    __syncthreads();
  }

  unsigned long long T = 0ull;
  if (c > need) {
    unsigned int rank = need;
    unsigned long long prefix = 0ull;
    for (int sh = 48; sh >= 0; sh -= 8) {
      hist[tid] = 0;
      __syncthreads();
      for (unsigned int i = tid; i < c; i += 256) {
        unsigned long long k = buf[i];
        if ((k >> (sh + 8)) == (prefix >> (sh + 8)))
          atomicAdd(&hist[(unsigned int)(k >> sh) & 255u], 1u);
      }
      __syncthreads();
      if (tid < 64) {
        unsigned int h0 = hist[4 * tid], h1 = hist[4 * tid + 1];
        unsigned int h2 = hist[4 * tid + 2], h3 = hist[4 * tid + 3];
        unsigned int gsum = h0 + h1 + h2 + h3;
        unsigned int s = gsum;
#pragma unroll
        for (int off = 1; off < 64; off <<= 1) {
          unsigned int o = __shfl_down(s, off, 64);
          s += (tid + off < 64) ? o : 0u;
        }
        unsigned int above = s - gsum;  // strictly higher digits
        unsigned int S3 = above, S2 = S3 + h3, S1 = S2 + h2, S0 = S1 + h1;
        if (S3 < rank && rank <= S3 + h3) { s_b = 4 * tid + 3; s_rank = rank - S3; }
        if (S2 < rank && rank <= S2 + h2) { s_b = 4 * tid + 2; s_rank = rank - S2; }
        if (S1 < rank && rank <= S1 + h1) { s_b = 4 * tid + 1; s_rank = rank - S1; }
        if (S0 < rank && rank <= S0 + h0) { s_b = 4 * tid + 0; s_rank = rank - S0; }
      }
      __syncthreads();
      prefix |= ((unsigned long long)s_b) << sh;
      rank = s_rank;
    }
    T = prefix;  // exact need-th largest key
  }

  if (tid == 0) s_cnt = 0;
  __syncthreads();
  for (unsigned int i = tid; i < c; i += 256) {
    unsigned long long k = buf[i];
    if (k >= T) {
      unsigned int pos = atomicAdd(&s_cnt, 1u);
      if (pos < NPTS) {
        uint32_t p = ~(uint32_t)k;
        pts[(size_t)m * NPTS + pos] = ((p >> 9) << 16) | (p & 511u);
      }
    }
  }
  __syncthreads();
  if (tid == 0) nsel[m] = s_cnt < need ? s_cnt : need;
}

// ---------------------------------------------------------------------------
// K3: Prim MST + fused finalize (unchanged from r11 — passed absmax 0).
// ---------------------------------------------------------------------------
__global__ __launch_bounds__(128, 1) void mst_kernel(
    const uint32_t* __restrict__ pts, const unsigned int* __restrict__ nsel,
    float* __restrict__ out) {
  const int wv = threadIdx.x >> 6;  // 0 = pred, 1 = mask
  const int m = blockIdx.x * 2 + wv;
  const int l = threadIdx.x & 63;
  const int n = (int)nsel[m];
  __shared__ float stp[2];

  unsigned int utp = 0;
  if (n > 1) {
    uint32_t pk[5], key[5];
    int px[5], py[5];
#pragma unroll
    for (int k = 0; k < 5; ++k) {
      int id = k * 64 + l;
      pk[k] = (id < n) ? pts[(size_t)m * NPTS + id] : 0u;
    }
    const uint32_t p0 = (uint32_t)__builtin_amdgcn_readlane((int)pk[0], 0);
    const int x0 = (int)(p0 >> 16), y0 = (int)(p0 & 0xFFFFu);
#pragma unroll
    for (int k = 0; k < 5; ++k) {
      int id = k * 64 + l;
      px[k] = (int)(pk[k] >> 16);
      py[k] = (int)(pk[k] & 0xFFFFu);
      if (id > 0 && id < n) {
        int dx = px[k] - x0, dy = py[k] - y0;
        key[k] = ((uint32_t)(__mul24(dx, dx) + __mul24(dy, dy)) << 9) |
                 (uint32_t)id;
      } else {
        key[k] = 0xFFFFFFFFu;
      }
    }

    for (int it = 0; it < n - 1; ++it) {
      uint32_t best = umin32(umin32(umin32(key[0], key[1]),
                                    umin32(key[2], key[3])), key[4]);
      best = wave_min_u32_bcast(best);
      utp += best >> 9;  // exact: sum < 2^31
      const int j = (int)(best & 511u);
      const int ko = j >> 6, lo = j & 63;
      uint32_t cp = pk[0];
#pragma unroll
      for (int k = 1; k < 5; ++k) cp = (ko == k) ? pk[k] : cp;
      const uint32_t pj = (uint32_t)__builtin_amdgcn_readlane((int)cp, lo);
      const int jx = (int)(pj >> 16), jy = (int)(pj & 0xFFFFu);
#pragma unroll
      for (int k = 0; k < 5; ++k) {
        int dx = px[k] - jx, dy = py[k] - jy;
        uint32_t nk = ((uint32_t)(__mul24(dx, dx) + __mul24(dy, dy)) << 9) |
                      (uint32_t)(k * 64 + l);
        uint32_t upd =
            (key[k] == 0xFFFFFFFFu) ? 0xFFFFFFFFu : umin32(key[k], nk);
        key[k] = (k == ko && l == lo) ? 0xFFFFFFFFu : upd;
      }
    }
  }
  if (l == 0) stp[wv] = (float)utp;
  __syncthreads();
  if (threadIdx.x == 0)
    atomicAdd(out, 1e-5f * fabsf(stp[1] - stp[0]) / 32.f);
}

// ---------------------------------------------------------------------------
extern "C" void kernel_launch(void* const* d_in, const int* in_sizes, int n_in,
                              void* d_out, int out_size, void* d_ws,
                              size_t ws_size, hipStream_t stream) {
  const float* mo = (const float*)d_in[0];
  const float* lb = (const float*)d_in[1];
  float* out = (float*)d_out;
  char* ws = (char*)d_ws;

  // ws layout (~3.26 MB):
  unsigned long long* bitmap = (unsigned long long*)ws;            // 2 MB
  unsigned long long* cand = (unsigned long long*)(ws + 2097152);  // 1 MB
  unsigned int* wcnts = (unsigned int*)(ws + 3145728);             // 32 KB
  unsigned int* bcnt  = (unsigned int*)(ws + 3178496);             // 8 KB
  unsigned int* nsel  = (unsigned int*)(ws + 3186688);             // 256 B
  uint32_t* pts       = (uint32_t*)(ws + 3186944);                 // 75 KB

  edge_collect_kernel<<<dim3(32, 64), 256, 0, stream>>>(mo, lb, bitmap, wcnts,
                                                        cand, bcnt, out);
  select_kernel<<<NMAPS, 256, 0, stream>>>(bitmap, wcnts, cand, bcnt, pts,
                                           nsel);
  mst_kernel<<<32, 128, 0, stream>>>(pts, nsel, out);
}